// Round 5
// baseline (410.794 us; speedup 1.0000x reference)
//
#include <hip/hip_runtime.h>

#define EPS 1e-5f
#define SLOPE 0.2f
#define MAXK 512
#define SEGCAP 12288   // segment = 256 dsts, mean 8192 edges, +45 sigma
#define PBATCH 16384

__device__ __forceinline__ float leaky(float z) {
    return fmaxf(z, 0.f) + SLOPE * fminf(z, 0.f);
}
__device__ __forceinline__ ushort f2bf(float f) {
    unsigned u = __float_as_uint(f);
    u += 0x7FFFu + ((u >> 16) & 1u);
    return (ushort)(u >> 16);
}
__device__ __forceinline__ float bf2f(ushort b) {
    return __uint_as_float(((unsigned)b) << 16);
}

// ---------- stage 0: coarse histogram over dst>>8 ----------
__global__ __launch_bounds__(256) void hist0(
    const int* __restrict__ ei, int E, int K, int* __restrict__ ghist) {
    __shared__ int h[MAXK];
    int t = threadIdx.x;
    for (int i = t; i < K; i += 256) h[i] = 0;
    __syncthreads();
    int base = blockIdx.x * PBATCH;
    for (int j = 0; j < PBATCH / 256; j++) {
        int e = base + j * 256 + t;
        if (e < E) atomicAdd(&h[ei[E + e] >> 8], 1);
    }
    __syncthreads();
    for (int i = t; i < K; i += 256) if (h[i]) atomicAdd(&ghist[i], h[i]);
}

// ---------- stage 1: exclusive scan of bucket counts (1 block) ----------
__global__ __launch_bounds__(512) void scanK(
    const int* __restrict__ ghist, int K, int* __restrict__ segbase,
    int* __restrict__ cursor) {
    __shared__ int sc[512];
    int t = threadIdx.x;
    int v = (t < K) ? ghist[t] : 0;
    sc[t] = v;
    __syncthreads();
    for (int off = 1; off < 512; off <<= 1) {
        int x = (t >= off) ? sc[t - off] : 0;
        __syncthreads();
        sc[t] += x;
        __syncthreads();
    }
    if (t < K) { int ex = sc[t] - v; segbase[t] = ex; cursor[t] = ex; }
    if (t == K - 1) segbase[K] = sc[t];
}

// ---------- stage 2: partition edges into coarse buckets (packed codes) ----
__global__ __launch_bounds__(256) void part1(
    const int* __restrict__ ei, int E, int K, int* __restrict__ cursor,
    unsigned* __restrict__ part) {
    __shared__ int h[MAXK];
    __shared__ int gp[MAXK];
    __shared__ int run[MAXK];
    int t = threadIdx.x;
    for (int i = t; i < K; i += 256) { h[i] = 0; run[i] = 0; }
    __syncthreads();
    int base = blockIdx.x * PBATCH;
    for (int j = 0; j < PBATCH / 256; j++) {
        int e = base + j * 256 + t;
        if (e < E) atomicAdd(&h[ei[E + e] >> 8], 1);
    }
    __syncthreads();
    for (int i = t; i < K; i += 256)
        gp[i] = h[i] ? atomicAdd(&cursor[i], h[i]) : 0;
    __syncthreads();
    for (int j = 0; j < PBATCH / 256; j++) {
        int e = base + j * 256 + t;
        if (e < E) {
            int s = ei[e], d = ei[E + e];
            int b = d >> 8;
            int p = atomicAdd(&run[b], 1);
            part[gp[b] + p] = ((unsigned)s << 8) | (unsigned)(d & 255);
        }
    }
}

// -- stage 3: per-segment LDS counting sort -> in-place CSR + degree hist ---
__global__ __launch_bounds__(256) void sortseg(
    const int* __restrict__ segbase, int N,
    unsigned* __restrict__ part, int* __restrict__ nodeofs, int* __restrict__ cnt,
    int* __restrict__ dh) {
    __shared__ int h2[256];
    __shared__ int sc[256];
    __shared__ int ex[256];
    __shared__ int dloc[128];
    __shared__ unsigned outb[SEGCAP];
    int b = blockIdx.x, t = threadIdx.x;
    int base = segbase[b];
    int sz = segbase[b + 1] - base;
    if (sz > SEGCAP) sz = SEGCAP;
    h2[t] = 0;
    if (t < 128) dloc[t] = 0;
    __syncthreads();
    for (int i = t; i < sz; i += 256) atomicAdd(&h2[part[base + i] & 255], 1);
    __syncthreads();
    int v = h2[t];
    sc[t] = v;
    __syncthreads();
    for (int off = 1; off < 256; off <<= 1) {
        int x = (t >= off) ? sc[t - off] : 0;
        __syncthreads();
        sc[t] += x;
        __syncthreads();
    }
    ex[t] = sc[t] - v;
    int n = b * 256 + t;
    if (n < N) {
        cnt[n] = v;
        nodeofs[n] = base + ex[t];
        atomicAdd(&dloc[min(v, 127)], 1);
    }
    __syncthreads();
    for (int i = t; i < sz; i += 256) {
        unsigned code = part[base + i];
        int p = atomicAdd(&ex[code & 255], 1);
        outb[p] = code >> 8;
    }
    if (t < 128 && dloc[t]) atomicAdd(&dh[t], dloc[t]);
    __syncthreads();
    for (int i = t; i < sz; i += 256) part[base + i] = outb[i];
}

// ---------- degree-sort: scan of 128-bin degree histogram (1 block) --------
__global__ __launch_bounds__(128) void dscan(
    const int* __restrict__ dh, int* __restrict__ dcur) {
    __shared__ int sc[128];
    int t = threadIdx.x;
    int v = dh[t];
    sc[t] = v;
    __syncthreads();
    for (int off = 1; off < 128; off <<= 1) {
        int x = (t >= off) ? sc[t - off] : 0;
        __syncthreads();
        sc[t] += x;
        __syncthreads();
    }
    dcur[t] = sc[t] - v;
}

// ---------- degree-sort: scatter node ids into degree-sorted perm ----------
__global__ __launch_bounds__(256) void dscatter(
    const int* __restrict__ cnt, int N, int* __restrict__ dcur,
    int* __restrict__ perm) {
    __shared__ int h[128], gp[128], run[128];
    int t = threadIdx.x;
    if (t < 128) { h[t] = 0; run[t] = 0; }
    __syncthreads();
    int n = blockIdx.x * 256 + t;
    int b = -1;
    if (n < N) { b = min(cnt[n], 127); atomicAdd(&h[b], 1); }
    __syncthreads();
    if (t < 128) gp[t] = h[t] ? atomicAdd(&dcur[t], h[t]) : 0;
    __syncthreads();
    if (n < N) { int p = atomicAdd(&run[b], 1); perm[gp[b] + p] = n; }
}

// ---------------- layer1 prep: h1 = x @ W1 (bf16 out) ; al_src/al_dst -------
__global__ __launch_bounds__(256) void prep1(
    const float* __restrict__ x, const float* __restrict__ W1,
    const float* __restrict__ as1, const float* __restrict__ ad1,
    ushort* __restrict__ h1b, float* __restrict__ al_s, float* __restrict__ al_d, int N) {
    __shared__ float Ws[64 * 64];
    __shared__ float xs[4][64];
    int t = threadIdx.x;
    for (int i = t; i < 64 * 64; i += 256) Ws[i] = W1[i];
    int r = t >> 6;
    int c = t & 63;
    int row = blockIdx.x * 4 + r;
    if (row < N) xs[r][c] = x[(size_t)row * 64 + c];
    __syncthreads();
    if (row >= N) return;
    float acc = 0.f;
#pragma unroll
    for (int k = 0; k < 64; k++) acc = fmaf(xs[r][k], Ws[k * 64 + c], acc);
    h1b[(size_t)row * 64 + c] = f2bf(acc);
    int head = c >> 5, cc = c & 31;
    float vs = acc * as1[head * 32 + cc];
    float vd = acc * ad1[head * 32 + cc];
#pragma unroll
    for (int off = 1; off < 32; off <<= 1) {
        vs += __shfl_xor(vs, off);
        vd += __shfl_xor(vd, off);
    }
    if (cc == 0) { al_s[row * 2 + head] = vs; al_d[row * 2 + head] = vd; }
}

// -- layer1 aggregation (fused softmax) + bias + LN + ELU, degree-ordered ---
// 16 lanes x 4 channels per node, 4 nodes per wave.
__global__ __launch_bounds__(256) void aggB1(
    const ushort* __restrict__ h1b, const float* __restrict__ als,
    const float* __restrict__ ald, const int* __restrict__ nodeofs,
    const int* __restrict__ cnt, const unsigned* __restrict__ csr,
    const int* __restrict__ perm,
    const float* __restrict__ b1, const float* __restrict__ g1,
    const float* __restrict__ bb1, ushort* __restrict__ h1out, int N) {
    int lane = threadIdx.x & 63;
    int sub = lane >> 4, q = lane & 15;
    int idx = blockIdx.x * 16 + (threadIdx.x >> 6) * 4 + sub;
    bool valid = idx < N;
    int nc = perm[min(idx, N - 1)];
    int head = q >> 3;
    const float2* als2 = (const float2*)als;
    const float2* ald2 = (const float2*)ald;
    float2 adv = ald2[nc], asv = als2[nc];
    float myad = head ? adv.y : adv.x;
    float wsf = __expf(leaky((head ? asv.y : asv.x) + myad));  // self weight
    const ushort4* h4 = (const ushort4*)h1b;
    ushort4 hs = h4[(unsigned)nc * 16 + q];
    float a0 = wsf * bf2f(hs.x), a1 = wsf * bf2f(hs.y);
    float a2 = wsf * bf2f(hs.z), a3 = wsf * bf2f(hs.w);
    float l = wsf;
    int ofs = valid ? nodeofs[nc] : 0;
    int deg = valid ? cnt[nc] : 0;
    int degm1 = max(deg - 1, 0);
    int degmax = deg;
#pragma unroll
    for (int off = 1; off < 64; off <<= 1) degmax = max(degmax, __shfl_xor(degmax, off));
    for (int e = 0; e < degmax; e += 4) {
        int j0 = ofs + min(e, degm1);
        int j1 = ofs + min(e + 1, degm1);
        int j2 = ofs + min(e + 2, degm1);
        int j3 = ofs + min(e + 3, degm1);
        int s0 = (int)csr[j0], s1 = (int)csr[j1];
        int s2 = (int)csr[j2], s3 = (int)csr[j3];
        float2 av0 = als2[s0], av1 = als2[s1];
        float2 av2 = als2[s2], av3 = als2[s3];
        ushort4 hv0 = h4[(unsigned)s0 * 16 + q];
        ushort4 hv1 = h4[(unsigned)s1 * 16 + q];
        ushort4 hv2 = h4[(unsigned)s2 * 16 + q];
        ushort4 hv3 = h4[(unsigned)s3 * 16 + q];
        float z0 = leaky((head ? av0.y : av0.x) + myad);
        float z1 = leaky((head ? av1.y : av1.x) + myad);
        float z2 = leaky((head ? av2.y : av2.x) + myad);
        float z3 = leaky((head ? av3.y : av3.x) + myad);
        float w0 = (e < deg) ? __expf(z0) : 0.f;
        float w1 = (e + 1 < deg) ? __expf(z1) : 0.f;
        float w2 = (e + 2 < deg) ? __expf(z2) : 0.f;
        float w3 = (e + 3 < deg) ? __expf(z3) : 0.f;
        l += (w0 + w1) + (w2 + w3);
        a0 = fmaf(w0, bf2f(hv0.x), a0); a1 = fmaf(w0, bf2f(hv0.y), a1);
        a2 = fmaf(w0, bf2f(hv0.z), a2); a3 = fmaf(w0, bf2f(hv0.w), a3);
        a0 = fmaf(w1, bf2f(hv1.x), a0); a1 = fmaf(w1, bf2f(hv1.y), a1);
        a2 = fmaf(w1, bf2f(hv1.z), a2); a3 = fmaf(w1, bf2f(hv1.w), a3);
        a0 = fmaf(w2, bf2f(hv2.x), a0); a1 = fmaf(w2, bf2f(hv2.y), a1);
        a2 = fmaf(w2, bf2f(hv2.z), a2); a3 = fmaf(w2, bf2f(hv2.w), a3);
        a0 = fmaf(w3, bf2f(hv3.x), a0); a1 = fmaf(w3, bf2f(hv3.y), a1);
        a2 = fmaf(w3, bf2f(hv3.z), a2); a3 = fmaf(w3, bf2f(hv3.w), a3);
    }
    if (!valid) return;
    float inv = 1.f / l;
    float4 bv = ((const float4*)b1)[q];
    float v0 = a0 * inv + bv.x, v1 = a1 * inv + bv.y;
    float v2 = a2 * inv + bv.z, v3 = a3 * inv + bv.w;
    float s1 = v0 + v1 + v2 + v3;
#pragma unroll
    for (int off = 1; off < 16; off <<= 1) s1 += __shfl_xor(s1, off);
    float mu = s1 * (1.f / 64.f);
    float d0 = v0 - mu, d1 = v1 - mu, d2 = v2 - mu, d3 = v3 - mu;
    float s2v = d0 * d0 + d1 * d1 + d2 * d2 + d3 * d3;
#pragma unroll
    for (int off = 1; off < 16; off <<= 1) s2v += __shfl_xor(s2v, off);
    float rs = rsqrtf(s2v * (1.f / 64.f) + EPS);
    float4 gv = ((const float4*)g1)[q];
    float4 bbv = ((const float4*)bb1)[q];
    float y0 = d0 * rs * gv.x + bbv.x;
    float y1 = d1 * rs * gv.y + bbv.y;
    float y2 = d2 * rs * gv.z + bbv.z;
    float y3 = d3 * rs * gv.w + bbv.w;
    y0 = (y0 > 0.f) ? y0 : (__expf(y0) - 1.f);
    y1 = (y1 > 0.f) ? y1 : (__expf(y1) - 1.f);
    y2 = (y2 > 0.f) ? y2 : (__expf(y2) - 1.f);
    y3 = (y3 > 0.f) ? y3 : (__expf(y3) - 1.f);
    ((ushort4*)h1out)[(unsigned)nc * 16 + q] =
        make_ushort4(f2bf(y0), f2bf(y1), f2bf(y2), f2bf(y3));
}

// ------------- layer2 prep: h2 = h1out(bf16) @ W2 (bf16 out) ; al2 ----------
__global__ __launch_bounds__(256) void prep2(
    const ushort* __restrict__ h1ob, const float* __restrict__ W2,
    const float* __restrict__ as2, const float* __restrict__ ad2,
    ushort* __restrict__ h2b, float* __restrict__ al_s, float* __restrict__ al_d, int N) {
    __shared__ float Ws[64 * 32];
    __shared__ float xs[8][64];
    int t = threadIdx.x;
    for (int i = t; i < 64 * 32; i += 256) Ws[i] = W2[i];
    int base = blockIdx.x * 8;
    const ushort4* hv4 = (const ushort4*)h1ob;
    for (int i = t; i < 128; i += 256) {
        int rr = i >> 4, kk = i & 15;
        int gr = base + rr;
        ushort4 u = (gr < N) ? hv4[(unsigned)gr * 16 + kk] : make_ushort4(0, 0, 0, 0);
        xs[rr][kk * 4 + 0] = bf2f(u.x);
        xs[rr][kk * 4 + 1] = bf2f(u.y);
        xs[rr][kk * 4 + 2] = bf2f(u.z);
        xs[rr][kk * 4 + 3] = bf2f(u.w);
    }
    __syncthreads();
    int r = t >> 5;
    int c = t & 31;
    int row = base + r;
    if (row >= N) return;
    float acc = 0.f;
#pragma unroll
    for (int k = 0; k < 64; k++) acc = fmaf(xs[r][k], Ws[k * 32 + c], acc);
    h2b[(size_t)row * 32 + c] = f2bf(acc);
    float vs = acc * as2[c], vd = acc * ad2[c];
#pragma unroll
    for (int off = 1; off < 32; off <<= 1) {
        vs += __shfl_xor(vs, off);
        vd += __shfl_xor(vd, off);
    }
    if (c == 0) { al_s[row] = vs; al_d[row] = vd; }
}

// -- layer2 aggregation + bias + LN + ELU + out projection, degree-ordered --
// 8 lanes x 4 channels per node, 8 nodes per wave.
__global__ __launch_bounds__(256) void aggB2(
    const ushort* __restrict__ h2b, const float* __restrict__ als,
    const float* __restrict__ ald, const int* __restrict__ nodeofs,
    const int* __restrict__ cnt, const unsigned* __restrict__ csr,
    const int* __restrict__ perm,
    const float* __restrict__ b2, const float* __restrict__ g2,
    const float* __restrict__ bb2, const float* __restrict__ Wout,
    const float* __restrict__ bout, float* __restrict__ out, int N) {
    int lane = threadIdx.x & 63;
    int sub = lane >> 3, q = lane & 7;
    int idx = blockIdx.x * 32 + (threadIdx.x >> 6) * 8 + sub;
    bool valid = idx < N;
    int nc = perm[min(idx, N - 1)];
    float myad = ald[nc];
    float wsf = __expf(leaky(als[nc] + myad));
    const ushort4* h4 = (const ushort4*)h2b;
    ushort4 hs = h4[(unsigned)nc * 8 + q];
    float a0 = wsf * bf2f(hs.x), a1 = wsf * bf2f(hs.y);
    float a2 = wsf * bf2f(hs.z), a3 = wsf * bf2f(hs.w);
    float l = wsf;
    int ofs = valid ? nodeofs[nc] : 0;
    int deg = valid ? cnt[nc] : 0;
    int degm1 = max(deg - 1, 0);
    int degmax = deg;
#pragma unroll
    for (int off = 1; off < 64; off <<= 1) degmax = max(degmax, __shfl_xor(degmax, off));
    for (int e = 0; e < degmax; e += 4) {
        int j0 = ofs + min(e, degm1);
        int j1 = ofs + min(e + 1, degm1);
        int j2 = ofs + min(e + 2, degm1);
        int j3 = ofs + min(e + 3, degm1);
        int s0 = (int)csr[j0], s1 = (int)csr[j1];
        int s2 = (int)csr[j2], s3 = (int)csr[j3];
        float z0 = leaky(als[s0] + myad);
        float z1 = leaky(als[s1] + myad);
        float z2 = leaky(als[s2] + myad);
        float z3 = leaky(als[s3] + myad);
        ushort4 hv0 = h4[(unsigned)s0 * 8 + q];
        ushort4 hv1 = h4[(unsigned)s1 * 8 + q];
        ushort4 hv2 = h4[(unsigned)s2 * 8 + q];
        ushort4 hv3 = h4[(unsigned)s3 * 8 + q];
        float w0 = (e < deg) ? __expf(z0) : 0.f;
        float w1 = (e + 1 < deg) ? __expf(z1) : 0.f;
        float w2 = (e + 2 < deg) ? __expf(z2) : 0.f;
        float w3 = (e + 3 < deg) ? __expf(z3) : 0.f;
        l += (w0 + w1) + (w2 + w3);
        a0 = fmaf(w0, bf2f(hv0.x), a0); a1 = fmaf(w0, bf2f(hv0.y), a1);
        a2 = fmaf(w0, bf2f(hv0.z), a2); a3 = fmaf(w0, bf2f(hv0.w), a3);
        a0 = fmaf(w1, bf2f(hv1.x), a0); a1 = fmaf(w1, bf2f(hv1.y), a1);
        a2 = fmaf(w1, bf2f(hv1.z), a2); a3 = fmaf(w1, bf2f(hv1.w), a3);
        a0 = fmaf(w2, bf2f(hv2.x), a0); a1 = fmaf(w2, bf2f(hv2.y), a1);
        a2 = fmaf(w2, bf2f(hv2.z), a2); a3 = fmaf(w2, bf2f(hv2.w), a3);
        a0 = fmaf(w3, bf2f(hv3.x), a0); a1 = fmaf(w3, bf2f(hv3.y), a1);
        a2 = fmaf(w3, bf2f(hv3.z), a2); a3 = fmaf(w3, bf2f(hv3.w), a3);
    }
    if (!valid) return;
    float inv = 1.f / l;
    float4 bv = ((const float4*)b2)[q];
    float v0 = a0 * inv + bv.x, v1 = a1 * inv + bv.y;
    float v2 = a2 * inv + bv.z, v3 = a3 * inv + bv.w;
    float s1 = v0 + v1 + v2 + v3;
#pragma unroll
    for (int off = 1; off < 8; off <<= 1) s1 += __shfl_xor(s1, off);
    float mu = s1 * (1.f / 32.f);
    float d0 = v0 - mu, d1 = v1 - mu, d2 = v2 - mu, d3 = v3 - mu;
    float s2v = d0 * d0 + d1 * d1 + d2 * d2 + d3 * d3;
#pragma unroll
    for (int off = 1; off < 8; off <<= 1) s2v += __shfl_xor(s2v, off);
    float rs = rsqrtf(s2v * (1.f / 32.f) + EPS);
    float4 gv = ((const float4*)g2)[q];
    float4 bbv = ((const float4*)bb2)[q];
    float y0 = d0 * rs * gv.x + bbv.x;
    float y1 = d1 * rs * gv.y + bbv.y;
    float y2 = d2 * rs * gv.z + bbv.z;
    float y3 = d3 * rs * gv.w + bbv.w;
    y0 = (y0 > 0.f) ? y0 : (__expf(y0) - 1.f);
    y1 = (y1 > 0.f) ? y1 : (__expf(y1) - 1.f);
    y2 = (y2 > 0.f) ? y2 : (__expf(y2) - 1.f);
    y3 = (y3 > 0.f) ? y3 : (__expf(y3) - 1.f);
    float4 wo = ((const float4*)Wout)[q];
    float p = y0 * wo.x + y1 * wo.y + y2 * wo.z + y3 * wo.w;
#pragma unroll
    for (int off = 1; off < 8; off <<= 1) p += __shfl_xor(p, off);
    if (q == 0) out[nc] = p + bout[0];
}

extern "C" void kernel_launch(void* const* d_in, const int* in_sizes, int n_in,
                              void* d_out, int out_size, void* d_ws, size_t ws_size,
                              hipStream_t stream) {
    const float* x    = (const float*)d_in[0];
    const int*   ei   = (const int*)d_in[1];
    const float* W1   = (const float*)d_in[2];
    const float* as1  = (const float*)d_in[3];
    const float* ad1  = (const float*)d_in[4];
    const float* b1   = (const float*)d_in[5];
    const float* g1   = (const float*)d_in[6];
    const float* bb1  = (const float*)d_in[7];
    const float* W2   = (const float*)d_in[8];
    const float* as2  = (const float*)d_in[9];
    const float* ad2  = (const float*)d_in[10];
    const float* b2   = (const float*)d_in[11];
    const float* g2   = (const float*)d_in[12];
    const float* bb2  = (const float*)d_in[13];
    const float* Wout = (const float*)d_in[14];
    const float* bout = (const float*)d_in[15];
    float* out = (float*)d_out;

    const int N = in_sizes[0] / 64;
    const int E = in_sizes[1] / 2;
    const int K = (N + 255) / 256;   // coarse buckets (<= MAXK)

    auto align_up = [](size_t v) { return (v + 255) & ~(size_t)255; };
    char* ws = (char*)d_ws;
    unsigned* part    = (unsigned*)ws; ws += align_up((size_t)E * 4);   // codes -> CSR (in place)
    int*      nodeofs = (int*)ws;      ws += align_up((size_t)N * 4);
    int*      cnt     = (int*)ws;      ws += align_up((size_t)N * 4);
    int*      perm    = (int*)ws;      ws += align_up((size_t)N * 4);
    int*      ghist   = (int*)ws;      ws += align_up((size_t)(MAXK) * 4);
    int*      segbase = (int*)ws;      ws += align_up((size_t)(MAXK + 1) * 4);
    int*      cursor  = (int*)ws;      ws += align_up((size_t)(MAXK) * 4);
    int*      dh      = (int*)ws;      ws += align_up((size_t)128 * 4);
    int*      dcur    = (int*)ws;      ws += align_up((size_t)128 * 4);
    ushort*   h1b     = (ushort*)ws;   ws += align_up((size_t)N * 64 * 2);
    ushort*   h1ob    = (ushort*)ws;   ws += align_up((size_t)N * 64 * 2);
    ushort*   h2b     = (ushort*)ws;   ws += align_up((size_t)N * 32 * 2);
    float*    al1s    = (float*)ws;    ws += align_up((size_t)N * 2 * 4);
    float*    al1d    = (float*)ws;    ws += align_up((size_t)N * 2 * 4);
    float*    al2s    = (float*)ws;    ws += align_up((size_t)N * 4);
    float*    al2d    = (float*)ws;    ws += align_up((size_t)N * 4);

    const int EB = (E + PBATCH - 1) / PBATCH;

    hipMemsetAsync(ghist, 0, (size_t)K * 4, stream);
    hipMemsetAsync(dh, 0, 128 * 4, stream);
    hist0<<<EB, 256, 0, stream>>>(ei, E, K, ghist);
    scanK<<<1, 512, 0, stream>>>(ghist, K, segbase, cursor);
    part1<<<EB, 256, 0, stream>>>(ei, E, K, cursor, part);
    sortseg<<<K, 256, 0, stream>>>(segbase, N, part, nodeofs, cnt, dh);
    dscan<<<1, 128, 0, stream>>>(dh, dcur);
    dscatter<<<(N + 255) / 256, 256, 0, stream>>>(cnt, N, dcur, perm);

    prep1<<<(N + 3) / 4, 256, 0, stream>>>(x, W1, as1, ad1, h1b, al1s, al1d, N);
    aggB1<<<(N + 15) / 16, 256, 0, stream>>>(h1b, al1s, al1d, nodeofs, cnt, part,
                                             perm, b1, g1, bb1, h1ob, N);
    prep2<<<(N + 7) / 8, 256, 0, stream>>>(h1ob, W2, as2, ad2, h2b, al2s, al2d, N);
    aggB2<<<(N + 31) / 32, 256, 0, stream>>>(h2b, al2s, al2d, nodeofs, cnt, part,
                                             perm, b2, g2, bb2, Wout, bout, out, N);
}

// Round 6
// 396.607 us; speedup vs baseline: 1.0358x; 1.0358x over previous
//
#include <hip/hip_runtime.h>

#define EPS 1e-5f
#define SLOPE 0.2f
#define MAXK 512
#define SEGCAP 12288   // segment = 256 dsts, mean 8192 edges, +45 sigma
#define PBATCH 16384

__device__ __forceinline__ float leaky(float z) {
    return fmaxf(z, 0.f) + SLOPE * fminf(z, 0.f);
}
__device__ __forceinline__ ushort f2bf(float f) {
    unsigned u = __float_as_uint(f);
    u += 0x7FFFu + ((u >> 16) & 1u);
    return (ushort)(u >> 16);
}
__device__ __forceinline__ float bf2f(ushort b) {
    return __uint_as_float(((unsigned)b) << 16);
}

// ---------- stage 0: coarse histogram over dst>>8 ----------
__global__ __launch_bounds__(256) void hist0(
    const int* __restrict__ ei, int E, int K, int* __restrict__ ghist) {
    __shared__ int h[MAXK];
    int t = threadIdx.x;
    for (int i = t; i < K; i += 256) h[i] = 0;
    __syncthreads();
    int base = blockIdx.x * PBATCH;
    for (int j = 0; j < PBATCH / 256; j++) {
        int e = base + j * 256 + t;
        if (e < E) atomicAdd(&h[ei[E + e] >> 8], 1);
    }
    __syncthreads();
    for (int i = t; i < K; i += 256) if (h[i]) atomicAdd(&ghist[i], h[i]);
}

// ---------- stage 1: exclusive scan of bucket counts (1 block) ----------
__global__ __launch_bounds__(512) void scanK(
    const int* __restrict__ ghist, int K, int* __restrict__ segbase,
    int* __restrict__ cursor) {
    __shared__ int sc[512];
    int t = threadIdx.x;
    int v = (t < K) ? ghist[t] : 0;
    sc[t] = v;
    __syncthreads();
    for (int off = 1; off < 512; off <<= 1) {
        int x = (t >= off) ? sc[t - off] : 0;
        __syncthreads();
        sc[t] += x;
        __syncthreads();
    }
    if (t < K) { int ex = sc[t] - v; segbase[t] = ex; cursor[t] = ex; }
    if (t == K - 1) segbase[K] = sc[t];
}

// ---------- stage 2: partition edges into coarse buckets (packed codes) ----
__global__ __launch_bounds__(256) void part1(
    const int* __restrict__ ei, int E, int K, int* __restrict__ cursor,
    unsigned* __restrict__ part) {
    __shared__ int h[MAXK];
    __shared__ int gp[MAXK];
    __shared__ int run[MAXK];
    int t = threadIdx.x;
    for (int i = t; i < K; i += 256) { h[i] = 0; run[i] = 0; }
    __syncthreads();
    int base = blockIdx.x * PBATCH;
    for (int j = 0; j < PBATCH / 256; j++) {
        int e = base + j * 256 + t;
        if (e < E) atomicAdd(&h[ei[E + e] >> 8], 1);
    }
    __syncthreads();
    for (int i = t; i < K; i += 256)
        gp[i] = h[i] ? atomicAdd(&cursor[i], h[i]) : 0;
    __syncthreads();
    for (int j = 0; j < PBATCH / 256; j++) {
        int e = base + j * 256 + t;
        if (e < E) {
            int s = ei[e], d = ei[E + e];
            int b = d >> 8;
            int p = atomicAdd(&run[b], 1);
            part[gp[b] + p] = ((unsigned)s << 8) | (unsigned)(d & 255);
        }
    }
}

// -- stage 3: per-segment LDS counting sort -> in-place CSR
//    + segment-local degree sort -> perm (degree-uniform, locality-preserving)
__global__ __launch_bounds__(256) void sortseg(
    const int* __restrict__ segbase, int N,
    unsigned* __restrict__ part, int* __restrict__ nodeofs, int* __restrict__ cnt,
    int* __restrict__ perm) {
    __shared__ int h2[256];
    __shared__ int sc[256];
    __shared__ int ex[256];
    __shared__ unsigned outb[SEGCAP];
    int b = blockIdx.x, t = threadIdx.x;
    int base = segbase[b];
    int sz = segbase[b + 1] - base;
    if (sz > SEGCAP) sz = SEGCAP;
    h2[t] = 0;
    __syncthreads();
    for (int i = t; i < sz; i += 256) atomicAdd(&h2[part[base + i] & 255], 1);
    __syncthreads();
    int v = h2[t];            // degree of node b*256+t
    sc[t] = v;
    __syncthreads();
    for (int off = 1; off < 256; off <<= 1) {
        int x = (t >= off) ? sc[t - off] : 0;
        __syncthreads();
        sc[t] += x;
        __syncthreads();
    }
    ex[t] = sc[t] - v;
    int n = b * 256 + t;
    if (n < N) { cnt[n] = v; nodeofs[n] = base + ex[t]; }
    __syncthreads();
    for (int i = t; i < sz; i += 256) {
        unsigned code = part[base + i];
        int p = atomicAdd(&ex[code & 255], 1);
        outb[p] = code >> 8;
    }
    __syncthreads();
    for (int i = t; i < sz; i += 256) part[base + i] = outb[i];
    // ---- segment-local degree sort (counting sort over capped degree) ----
    __syncthreads();
    h2[t] = 0;
    __syncthreads();
    int dbin = min(v, 255);
    if (n < N) atomicAdd(&h2[dbin], 1);
    __syncthreads();
    int hv = h2[t];
    sc[t] = hv;
    __syncthreads();
    for (int off = 1; off < 256; off <<= 1) {
        int x = (t >= off) ? sc[t - off] : 0;
        __syncthreads();
        sc[t] += x;
        __syncthreads();
    }
    ex[t] = sc[t] - hv;
    __syncthreads();
    if (n < N) {
        int r = atomicAdd(&ex[dbin], 1);
        perm[b * 256 + r] = n;
    }
}

// ---------------- layer1 prep: h1 = x @ W1 (bf16 out) ; al_src/al_dst -------
__global__ __launch_bounds__(256) void prep1(
    const float* __restrict__ x, const float* __restrict__ W1,
    const float* __restrict__ as1, const float* __restrict__ ad1,
    ushort* __restrict__ h1b, float* __restrict__ al_s, float* __restrict__ al_d, int N) {
    __shared__ float Ws[64 * 64];
    __shared__ float xs[4][64];
    int t = threadIdx.x;
    for (int i = t; i < 64 * 64; i += 256) Ws[i] = W1[i];
    int r = t >> 6;
    int c = t & 63;
    int row = blockIdx.x * 4 + r;
    if (row < N) xs[r][c] = x[(size_t)row * 64 + c];
    __syncthreads();
    if (row >= N) return;
    float acc = 0.f;
#pragma unroll
    for (int k = 0; k < 64; k++) acc = fmaf(xs[r][k], Ws[k * 64 + c], acc);
    h1b[(size_t)row * 64 + c] = f2bf(acc);
    int head = c >> 5, cc = c & 31;
    float vs = acc * as1[head * 32 + cc];
    float vd = acc * ad1[head * 32 + cc];
#pragma unroll
    for (int off = 1; off < 32; off <<= 1) {
        vs += __shfl_xor(vs, off);
        vd += __shfl_xor(vd, off);
    }
    if (cc == 0) { al_s[row * 2 + head] = vs; al_d[row * 2 + head] = vd; }
}

// -- layer1 aggregation: lane-cooperative 16-edge batches + LN + ELU --------
// 16 lanes x 4 channels per node, 4 nodes per wave.
__global__ __launch_bounds__(256) void aggB1(
    const ushort* __restrict__ h1b, const float* __restrict__ als,
    const float* __restrict__ ald, const int* __restrict__ nodeofs,
    const int* __restrict__ cnt, const unsigned* __restrict__ csr,
    const int* __restrict__ perm,
    const float* __restrict__ b1, const float* __restrict__ g1,
    const float* __restrict__ bb1, ushort* __restrict__ h1out, int N) {
    int lane = threadIdx.x & 63;
    int grp = lane >> 4, q = lane & 15;
    int gbase = grp << 4;
    int idx = blockIdx.x * 16 + (threadIdx.x >> 6) * 4 + grp;
    bool valid = idx < N;
    int nc = perm[min(idx, N - 1)];
    int head = q >> 3;
    const float2* als2 = (const float2*)als;
    const float2* ald2 = (const float2*)ald;
    float2 adv = ald2[nc], asv = als2[nc];
    float ad0 = adv.x, ad1v = adv.y;
    float wsf = __expf(leaky((head ? asv.y : asv.x) + (head ? ad1v : ad0)));
    const ushort4* h4 = (const ushort4*)h1b;
    ushort4 hs = h4[(unsigned)nc * 16 + q];
    float a0 = wsf * bf2f(hs.x), a1 = wsf * bf2f(hs.y);
    float a2 = wsf * bf2f(hs.z), a3 = wsf * bf2f(hs.w);
    float l0p = 0.f, l1p = 0.f;
    int ofs = valid ? nodeofs[nc] : 0;
    int deg = valid ? cnt[nc] : 0;
    int degm1 = max(deg - 1, 0);
    int degmax = deg;              // deg uniform within 16-lane group
    degmax = max(degmax, __shfl_xor(degmax, 16));
    degmax = max(degmax, __shfl_xor(degmax, 32));
    for (int eb = 0; eb < degmax; eb += 16) {
        int j = ofs + min(eb + q, degm1);
        int sq = min((int)csr[j], N - 1);
        float2 av = als2[sq];
        float z0 = leaky(av.x + ad0);
        float z1 = leaky(av.y + ad1v);
        bool ev = (eb + q < deg);
        float w0q = ev ? __expf(z0) : 0.f;
        float w1q = ev ? __expf(z1) : 0.f;
        l0p += w0q;
        l1p += w1q;
#pragma unroll
        for (int jj = 0; jj < 16; jj++) {
            int s = __shfl(sq, gbase + jj);
            float w0 = __shfl(w0q, gbase + jj);
            float w1 = __shfl(w1q, gbase + jj);
            float w = head ? w1 : w0;
            ushort4 hv = h4[(unsigned)s * 16 + q];
            a0 = fmaf(w, bf2f(hv.x), a0);
            a1 = fmaf(w, bf2f(hv.y), a1);
            a2 = fmaf(w, bf2f(hv.z), a2);
            a3 = fmaf(w, bf2f(hv.w), a3);
        }
    }
#pragma unroll
    for (int off = 1; off < 16; off <<= 1) {
        l0p += __shfl_xor(l0p, off);
        l1p += __shfl_xor(l1p, off);
    }
    if (!valid) return;
    float l = (head ? l1p : l0p) + wsf;
    float inv = 1.f / l;
    float4 bv = ((const float4*)b1)[q];
    float v0 = a0 * inv + bv.x, v1 = a1 * inv + bv.y;
    float v2 = a2 * inv + bv.z, v3 = a3 * inv + bv.w;
    float s1 = v0 + v1 + v2 + v3;
#pragma unroll
    for (int off = 1; off < 16; off <<= 1) s1 += __shfl_xor(s1, off);
    float mu = s1 * (1.f / 64.f);
    float d0 = v0 - mu, d1 = v1 - mu, d2 = v2 - mu, d3 = v3 - mu;
    float s2v = d0 * d0 + d1 * d1 + d2 * d2 + d3 * d3;
#pragma unroll
    for (int off = 1; off < 16; off <<= 1) s2v += __shfl_xor(s2v, off);
    float rs = rsqrtf(s2v * (1.f / 64.f) + EPS);
    float4 gv = ((const float4*)g1)[q];
    float4 bbv = ((const float4*)bb1)[q];
    float y0 = d0 * rs * gv.x + bbv.x;
    float y1 = d1 * rs * gv.y + bbv.y;
    float y2 = d2 * rs * gv.z + bbv.z;
    float y3 = d3 * rs * gv.w + bbv.w;
    y0 = (y0 > 0.f) ? y0 : (__expf(y0) - 1.f);
    y1 = (y1 > 0.f) ? y1 : (__expf(y1) - 1.f);
    y2 = (y2 > 0.f) ? y2 : (__expf(y2) - 1.f);
    y3 = (y3 > 0.f) ? y3 : (__expf(y3) - 1.f);
    ((ushort4*)h1out)[(unsigned)nc * 16 + q] =
        make_ushort4(f2bf(y0), f2bf(y1), f2bf(y2), f2bf(y3));
}

// ------------- layer2 prep: h2 = h1out(bf16) @ W2 (bf16 out) ; al2 ----------
__global__ __launch_bounds__(256) void prep2(
    const ushort* __restrict__ h1ob, const float* __restrict__ W2,
    const float* __restrict__ as2, const float* __restrict__ ad2,
    ushort* __restrict__ h2b, float* __restrict__ al_s, float* __restrict__ al_d, int N) {
    __shared__ float Ws[64 * 32];
    __shared__ float xs[8][64];
    int t = threadIdx.x;
    for (int i = t; i < 64 * 32; i += 256) Ws[i] = W2[i];
    int base = blockIdx.x * 8;
    const ushort4* hv4 = (const ushort4*)h1ob;
    for (int i = t; i < 128; i += 256) {
        int rr = i >> 4, kk = i & 15;
        int gr = base + rr;
        ushort4 u = (gr < N) ? hv4[(unsigned)gr * 16 + kk] : make_ushort4(0, 0, 0, 0);
        xs[rr][kk * 4 + 0] = bf2f(u.x);
        xs[rr][kk * 4 + 1] = bf2f(u.y);
        xs[rr][kk * 4 + 2] = bf2f(u.z);
        xs[rr][kk * 4 + 3] = bf2f(u.w);
    }
    __syncthreads();
    int r = t >> 5;
    int c = t & 31;
    int row = base + r;
    if (row >= N) return;
    float acc = 0.f;
#pragma unroll
    for (int k = 0; k < 64; k++) acc = fmaf(xs[r][k], Ws[k * 32 + c], acc);
    h2b[(size_t)row * 32 + c] = f2bf(acc);
    float vs = acc * as2[c], vd = acc * ad2[c];
#pragma unroll
    for (int off = 1; off < 32; off <<= 1) {
        vs += __shfl_xor(vs, off);
        vd += __shfl_xor(vd, off);
    }
    if (c == 0) { al_s[row] = vs; al_d[row] = vd; }
}

// -- layer2 aggregation: 8-edge batches + bias + LN + ELU + out projection --
// 8 lanes x 4 channels per node, 8 nodes per wave.
__global__ __launch_bounds__(256) void aggB2(
    const ushort* __restrict__ h2b, const float* __restrict__ als,
    const float* __restrict__ ald, const int* __restrict__ nodeofs,
    const int* __restrict__ cnt, const unsigned* __restrict__ csr,
    const int* __restrict__ perm,
    const float* __restrict__ b2, const float* __restrict__ g2,
    const float* __restrict__ bb2, const float* __restrict__ Wout,
    const float* __restrict__ bout, float* __restrict__ out, int N) {
    int lane = threadIdx.x & 63;
    int grp = lane >> 3, q = lane & 7;
    int gbase = grp << 3;
    int idx = blockIdx.x * 32 + (threadIdx.x >> 6) * 8 + grp;
    bool valid = idx < N;
    int nc = perm[min(idx, N - 1)];
    float myad = ald[nc];
    float wsf = __expf(leaky(als[nc] + myad));
    const ushort4* h4 = (const ushort4*)h2b;
    ushort4 hs = h4[(unsigned)nc * 8 + q];
    float a0 = wsf * bf2f(hs.x), a1 = wsf * bf2f(hs.y);
    float a2 = wsf * bf2f(hs.z), a3 = wsf * bf2f(hs.w);
    float lp = 0.f;
    int ofs = valid ? nodeofs[nc] : 0;
    int deg = valid ? cnt[nc] : 0;
    int degm1 = max(deg - 1, 0);
    int degmax = deg;              // uniform within 8-lane group
    degmax = max(degmax, __shfl_xor(degmax, 8));
    degmax = max(degmax, __shfl_xor(degmax, 16));
    degmax = max(degmax, __shfl_xor(degmax, 32));
    for (int eb = 0; eb < degmax; eb += 8) {
        int j = ofs + min(eb + q, degm1);
        int sq = min((int)csr[j], N - 1);
        float z = leaky(als[sq] + myad);
        float wq = (eb + q < deg) ? __expf(z) : 0.f;
        lp += wq;
#pragma unroll
        for (int jj = 0; jj < 8; jj++) {
            int s = __shfl(sq, gbase + jj);
            float w = __shfl(wq, gbase + jj);
            ushort4 hv = h4[(unsigned)s * 8 + q];
            a0 = fmaf(w, bf2f(hv.x), a0);
            a1 = fmaf(w, bf2f(hv.y), a1);
            a2 = fmaf(w, bf2f(hv.z), a2);
            a3 = fmaf(w, bf2f(hv.w), a3);
        }
    }
#pragma unroll
    for (int off = 1; off < 8; off <<= 1) lp += __shfl_xor(lp, off);
    if (!valid) return;
    float l = lp + wsf;
    float inv = 1.f / l;
    float4 bv = ((const float4*)b2)[q];
    float v0 = a0 * inv + bv.x, v1 = a1 * inv + bv.y;
    float v2 = a2 * inv + bv.z, v3 = a3 * inv + bv.w;
    float s1 = v0 + v1 + v2 + v3;
#pragma unroll
    for (int off = 1; off < 8; off <<= 1) s1 += __shfl_xor(s1, off);
    float mu = s1 * (1.f / 32.f);
    float d0 = v0 - mu, d1 = v1 - mu, d2 = v2 - mu, d3 = v3 - mu;
    float s2v = d0 * d0 + d1 * d1 + d2 * d2 + d3 * d3;
#pragma unroll
    for (int off = 1; off < 8; off <<= 1) s2v += __shfl_xor(s2v, off);
    float rs = rsqrtf(s2v * (1.f / 32.f) + EPS);
    float4 gv = ((const float4*)g2)[q];
    float4 bbv = ((const float4*)bb2)[q];
    float y0 = d0 * rs * gv.x + bbv.x;
    float y1 = d1 * rs * gv.y + bbv.y;
    float y2 = d2 * rs * gv.z + bbv.z;
    float y3 = d3 * rs * gv.w + bbv.w;
    y0 = (y0 > 0.f) ? y0 : (__expf(y0) - 1.f);
    y1 = (y1 > 0.f) ? y1 : (__expf(y1) - 1.f);
    y2 = (y2 > 0.f) ? y2 : (__expf(y2) - 1.f);
    y3 = (y3 > 0.f) ? y3 : (__expf(y3) - 1.f);
    float4 wo = ((const float4*)Wout)[q];
    float p = y0 * wo.x + y1 * wo.y + y2 * wo.z + y3 * wo.w;
#pragma unroll
    for (int off = 1; off < 8; off <<= 1) p += __shfl_xor(p, off);
    if (q == 0) out[nc] = p + bout[0];
}

extern "C" void kernel_launch(void* const* d_in, const int* in_sizes, int n_in,
                              void* d_out, int out_size, void* d_ws, size_t ws_size,
                              hipStream_t stream) {
    const float* x    = (const float*)d_in[0];
    const int*   ei   = (const int*)d_in[1];
    const float* W1   = (const float*)d_in[2];
    const float* as1  = (const float*)d_in[3];
    const float* ad1  = (const float*)d_in[4];
    const float* b1   = (const float*)d_in[5];
    const float* g1   = (const float*)d_in[6];
    const float* bb1  = (const float*)d_in[7];
    const float* W2   = (const float*)d_in[8];
    const float* as2  = (const float*)d_in[9];
    const float* ad2  = (const float*)d_in[10];
    const float* b2   = (const float*)d_in[11];
    const float* g2   = (const float*)d_in[12];
    const float* bb2  = (const float*)d_in[13];
    const float* Wout = (const float*)d_in[14];
    const float* bout = (const float*)d_in[15];
    float* out = (float*)d_out;

    const int N = in_sizes[0] / 64;
    const int E = in_sizes[1] / 2;
    const int K = (N + 255) / 256;   // coarse buckets (<= MAXK)

    auto align_up = [](size_t v) { return (v + 255) & ~(size_t)255; };
    char* ws = (char*)d_ws;
    unsigned* part    = (unsigned*)ws; ws += align_up((size_t)E * 4);   // codes -> CSR (in place)
    int*      nodeofs = (int*)ws;      ws += align_up((size_t)N * 4);
    int*      cnt     = (int*)ws;      ws += align_up((size_t)N * 4);
    int*      perm    = (int*)ws;      ws += align_up((size_t)(K * 256) * 4);
    int*      ghist   = (int*)ws;      ws += align_up((size_t)(MAXK) * 4);
    int*      segbase = (int*)ws;      ws += align_up((size_t)(MAXK + 1) * 4);
    int*      cursor  = (int*)ws;      ws += align_up((size_t)(MAXK) * 4);
    ushort*   h1b     = (ushort*)ws;   ws += align_up((size_t)N * 64 * 2);
    ushort*   h1ob    = (ushort*)ws;   ws += align_up((size_t)N * 64 * 2);
    ushort*   h2b     = (ushort*)ws;   ws += align_up((size_t)N * 32 * 2);
    float*    al1s    = (float*)ws;    ws += align_up((size_t)N * 2 * 4);
    float*    al1d    = (float*)ws;    ws += align_up((size_t)N * 2 * 4);
    float*    al2s    = (float*)ws;    ws += align_up((size_t)N * 4);
    float*    al2d    = (float*)ws;    ws += align_up((size_t)N * 4);

    const int EB = (E + PBATCH - 1) / PBATCH;

    hipMemsetAsync(ghist, 0, (size_t)K * 4, stream);
    hist0<<<EB, 256, 0, stream>>>(ei, E, K, ghist);
    scanK<<<1, 512, 0, stream>>>(ghist, K, segbase, cursor);
    part1<<<EB, 256, 0, stream>>>(ei, E, K, cursor, part);
    sortseg<<<K, 256, 0, stream>>>(segbase, N, part, nodeofs, cnt, perm);

    prep1<<<(N + 3) / 4, 256, 0, stream>>>(x, W1, as1, ad1, h1b, al1s, al1d, N);
    aggB1<<<(N + 15) / 16, 256, 0, stream>>>(h1b, al1s, al1d, nodeofs, cnt, part,
                                             perm, b1, g1, bb1, h1ob, N);
    prep2<<<(N + 7) / 8, 256, 0, stream>>>(h1ob, W2, as2, ad2, h2b, al2s, al2d, N);
    aggB2<<<(N + 31) / 32, 256, 0, stream>>>(h2b, al2s, al2d, nodeofs, cnt, part,
                                             perm, b2, g2, bb2, Wout, bout, out, N);
}